// Round 5
// baseline (209.225 us; speedup 1.0000x reference)
//
#include <hip/hip_runtime.h>
#include <math.h>

#define B 8
#define L 4096
#define D 64
#define TD 128          // 2*D
#define G 64
#define KS 16
#define NSLOT 1024      // G*KS
#define EPS 1e-5f
#define MARGIN 0.04f

// ---- workspace layout (float offsets) ----
#define OFF_SSUM 0        // 512 fp32
#define OFF_WGT  512      // 8192 fp32 [k][g] 128x64   (routing recompute)
#define OFF_WST  8704     // 2048 fp32 [k][s] 128x16   (routing recompute)
#define OFF_MW0B 10752    // 16384 bf16 (8192 f)  MFMA B-frag
#define OFF_MW1B 18944    // 8192 bf16 (4096 f)
#define OFF_GW0B 23040    // 8192 bf16 (4096 f)
#define OFF_WGB  27136    // 8192 bf16 (4096 f)
#define OFF_WSB  31232    // 2048 bf16 (1024 f)
#define OFF_UW0B 32256    // 16384 bf16 (8192 f)
#define OFF_UW1B 40448    // 8192 bf16 (4096 f)
#define OFF_SLOT 44544    // 32768 ints
#define OFF_INC  77312    // 524288 fp32 incoming [B][N][D]
// total 601600 floats ≈ 2.41 MB

typedef __attribute__((ext_vector_type(8))) short short8;
typedef __attribute__((ext_vector_type(4))) float f32x4;

__device__ __forceinline__ float gelu_exact(float x) {
    return 0.5f * x * (1.0f + erff(x * 0.70710678118654752f));
}

__device__ __forceinline__ unsigned short f2bf(float f) {
    unsigned u = __float_as_uint(f);
    u += 0x7FFFu + ((u >> 16) & 1u);        // round-to-nearest-even
    return (unsigned short)(u >> 16);
}

// B-fragment mapping for 16x16x32 bf16 MFMA, 16-col tiles, K=128.
__device__ __forceinline__ void fragmap(int r, int& j, int& k) {
    int e = r & 7, l = (r >> 3) & 63, ks = (r >> 9) & 3, jt = r >> 11;
    j = jt * 16 + (l & 15);
    k = ks * 32 + (l >> 4) * 8 + e;
}

// ---------------- prep: weight transposes/frag-packs + state summary ----------------
__global__ __launch_bounds__(256) void prep_kernel(
    const float* __restrict__ S, const float* __restrict__ Wg,
    const float* __restrict__ Ws, const float* __restrict__ mw0,
    const float* __restrict__ mw1, const float* __restrict__ gw0,
    const float* __restrict__ uw0, const float* __restrict__ uw1,
    float* __restrict__ ws)
{
    int blk = blockIdx.x;
    if (blk < 304) {
        int idx = blk * 256 + threadIdx.x;   // [0, 77824)
        unsigned short* wsu = (unsigned short*)ws;
        int j, k;
        if (idx < 8192) {                        // WGT fp32 [k][g]
            int kk = idx >> 6, g = idx & 63;
            ws[OFF_WGT + idx] = Wg[g * TD + kk];
        } else if (idx < 10240) {                // WST fp32 [k][s]
            int r = idx - 8192; int kk = r >> 4, s = r & 15;
            ws[OFF_WST + r] = Ws[s * TD + kk];
        } else if (idx < 26624) {                // MW0B
            int r = idx - 10240; fragmap(r, j, k);
            wsu[OFF_MW0B * 2 + r] = f2bf(mw0[j * TD + k]);
        } else if (idx < 34816) {                // MW1B
            int r = idx - 26624; fragmap(r, j, k);
            wsu[OFF_MW1B * 2 + r] = f2bf(mw1[j * TD + k]);
        } else if (idx < 43008) {                // GW0B
            int r = idx - 34816; fragmap(r, j, k);
            wsu[OFF_GW0B * 2 + r] = f2bf(gw0[j * TD + k]);
        } else if (idx < 51200) {                // WGB
            int r = idx - 43008; fragmap(r, j, k);
            wsu[OFF_WGB * 2 + r] = f2bf(Wg[j * TD + k]);
        } else if (idx < 53248) {                // WSB (16 cols)
            int r = idx - 51200; fragmap(r, j, k);
            wsu[OFF_WSB * 2 + r] = f2bf(Ws[j * TD + k]);
        } else if (idx < 69632) {                // UW0B
            int r = idx - 53248; fragmap(r, j, k);
            wsu[OFF_UW0B * 2 + r] = f2bf(uw0[j * TD + k]);
        } else if (idx < 77824) {                // UW1B
            int r = idx - 69632; fragmap(r, j, k);
            wsu[OFF_UW1B * 2 + r] = f2bf(uw1[j * TD + k]);
        }
    } else {
        // state summary — SERIAL add order (bit-identical to round-4; feeds routing)
        int b = blk - 304;
        int d = threadIdx.x;
        if (d < D) {
            const float* Sp = S + (size_t)b * NSLOT * D + d;
            float acc = 0.f;
            for (int n0 = 0; n0 < NSLOT; n0 += 16) {
                float v[16];
                #pragma unroll
                for (int u = 0; u < 16; ++u) v[u] = Sp[(size_t)(n0 + u) * D];
                #pragma unroll
                for (int u = 0; u < 16; ++u) acc += v[u];
            }
            ws[OFF_SSUM + b * D + d] = acc * (1.0f / NSLOT);
        }
    }
}

// ---------------- routing: bf16 MFMA logits + exact fp32 recompute for near-ties ----------------
__global__ __launch_bounds__(256) void routing_kernel(
    const float* __restrict__ X, float* __restrict__ ws)
{
    __shared__ __align__(16) unsigned short xsl[64 * 136];
    __shared__ float lgl[64][85];     // cols 0..63 = group logits, 64..79 = slot logits
    __shared__ int   slotl[64];
    __shared__ unsigned char flags[64];
    __shared__ int   flist[64];
    __shared__ int   flagcnt;

    const int tid  = threadIdx.x;
    const int tok0 = blockIdx.x * 64;
    const int b    = tok0 >> 12;      // / L

    if (tid == 0) flagcnt = 0;

    // ---- stage XS as bf16 (same as msg_kernel) ----
    {
        int t = tid >> 2, q = tid & 3;
        unsigned short tmp[32];
        if (q < 2) {
            const float* Xp = X + (size_t)(tok0 + t) * D + q * 32;
            #pragma unroll
            for (int u = 0; u < 8; ++u) {
                float4 v = *(const float4*)(Xp + u * 4);
                tmp[u*4+0] = f2bf(v.x); tmp[u*4+1] = f2bf(v.y);
                tmp[u*4+2] = f2bf(v.z); tmp[u*4+3] = f2bf(v.w);
            }
        } else {
            const float* Sp = ws + OFF_SSUM + b * D + (q - 2) * 32;
            #pragma unroll
            for (int u = 0; u < 32; ++u) tmp[u] = f2bf(Sp[u]);
        }
        #pragma unroll
        for (int s = 0; s < 4; ++s)
            *(short8*)&xsl[t * 136 + (q * 4 + s) * 8] = *(const short8*)&tmp[s * 8];
    }
    __syncthreads();

    const int w  = tid >> 6;
    const int l  = tid & 63;
    const int lr = l & 15;
    const int lk = l >> 4;
    const unsigned short* wsu = (const unsigned short*)ws;

    // ---- MFMA logits ----
    if (w < 2) {          // group logits: wave w -> col-tiles {2w, 2w+1}
        f32x4 acc[2][4];
        #pragma unroll
        for (int c2 = 0; c2 < 2; ++c2)
            #pragma unroll
            for (int tt = 0; tt < 4; ++tt) acc[c2][tt] = (f32x4){0.f,0.f,0.f,0.f};
        for (int ks = 0; ks < 4; ++ks) {
            short8 a[4];
            #pragma unroll
            for (int tt = 0; tt < 4; ++tt)
                a[tt] = *(const short8*)&xsl[(tt * 16 + lr) * 136 + (ks * 4 + lk) * 8];
            #pragma unroll
            for (int c2 = 0; c2 < 2; ++c2) {
                int jt = w * 2 + c2;
                short8 bb = *(const short8*)&wsu[OFF_WGB * 2 + ((jt * 4 + ks) * 64 + l) * 8];
                #pragma unroll
                for (int tt = 0; tt < 4; ++tt)
                    acc[c2][tt] = __builtin_amdgcn_mfma_f32_16x16x32_bf16(a[tt], bb, acc[c2][tt], 0, 0, 0);
            }
        }
        #pragma unroll
        for (int c2 = 0; c2 < 2; ++c2) {
            int j = (w * 2 + c2) * 16 + lr;
            #pragma unroll
            for (int tt = 0; tt < 4; ++tt)
                #pragma unroll
                for (int r = 0; r < 4; ++r)
                    lgl[tt * 16 + lk * 4 + r][j] = acc[c2][tt][r];
        }
    } else {              // slot logits: waves 2,3 split token-tiles
        f32x4 acc[2];
        acc[0] = (f32x4){0.f,0.f,0.f,0.f}; acc[1] = (f32x4){0.f,0.f,0.f,0.f};
        int ttb = (w - 2) * 2;
        for (int ks = 0; ks < 4; ++ks) {
            short8 a0 = *(const short8*)&xsl[((ttb    ) * 16 + lr) * 136 + (ks * 4 + lk) * 8];
            short8 a1 = *(const short8*)&xsl[((ttb + 1) * 16 + lr) * 136 + (ks * 4 + lk) * 8];
            short8 bb = *(const short8*)&wsu[OFF_WSB * 2 + (ks * 64 + l) * 8];
            acc[0] = __builtin_amdgcn_mfma_f32_16x16x32_bf16(a0, bb, acc[0], 0, 0, 0);
            acc[1] = __builtin_amdgcn_mfma_f32_16x16x32_bf16(a1, bb, acc[1], 0, 0, 0);
        }
        #pragma unroll
        for (int tt2 = 0; tt2 < 2; ++tt2)
            #pragma unroll
            for (int r = 0; r < 4; ++r)
                lgl[(ttb + tt2) * 16 + lk * 4 + r][64 + lr] = acc[tt2][r];
    }
    __syncthreads();

    // ---- per-token scan: argmax + top-2 gap flag ----
    if (tid < 64) {
        int t = tid;
        float bv = lgl[t][0], g2 = -1e30f; int bg = 0;
        for (int g = 1; g < G; ++g) {
            float v = lgl[t][g];
            if (v > bv) { g2 = bv; bv = v; bg = g; } else if (v > g2) g2 = v;
        }
        float sv = lgl[t][64], s2 = -1e30f; int bs = 0;
        for (int s = 1; s < KS; ++s) {
            float v = lgl[t][64 + s];
            if (v > sv) { s2 = sv; sv = v; bs = s; } else if (v > s2) s2 = v;
        }
        bool fl = (bv - g2 < MARGIN) || (sv - s2 < MARGIN);
        flags[t] = fl;
        slotl[t] = bg * KS + bs;
        if (fl) { int i = atomicAdd(&flagcnt, 1); flist[i] = t; }
    }
    __syncthreads();

    // ---- exact fp32 recompute for flagged tokens (bit-identical to round-4 path) ----
    int nf = flagcnt;
    for (int fi = 0; fi < nf; ++fi) {
        int t = flist[fi];
        if (tid < 80) {
            bool isg = tid < 64;
            const float* wp = isg ? (ws + OFF_WGT + tid) : (ws + OFF_WST + (tid - 64));
            int stride = isg ? G : KS;
            const float* xp = X + (size_t)(tok0 + t) * D;
            const float* sp = ws + OFF_SSUM + b * D;
            float acc = 0.f;
            #pragma unroll 8
            for (int k = 0; k < 64; ++k) acc += wp[k * stride] * xp[k];
            #pragma unroll 8
            for (int k = 0; k < 64; ++k) acc += wp[(64 + k) * stride] * sp[k];
            lgl[t][tid] = acc;
        }
        __syncthreads();
    }
    if (tid < 64 && flags[tid]) {
        int t = tid;
        float bv = lgl[t][0]; int bg = 0;
        for (int g = 1; g < G; ++g) { float v = lgl[t][g]; if (v > bv) { bv = v; bg = g; } }
        float sv = lgl[t][64]; int bs = 0;
        for (int s = 1; s < KS; ++s) { float v = lgl[t][64 + s]; if (v > sv) { sv = v; bs = s; } }
        slotl[t] = bg * KS + bs;
    }
    __syncthreads();
    if (tid < 64) ((int*)(ws + OFF_SLOT))[tok0 + tid] = slotl[tid];
}

// ---------------- msg kernel: bf16 MFMA MLPs + gate + scatter (unchanged structure) ----------------
__global__ __launch_bounds__(256) void msg_kernel(
    const float* __restrict__ X,
    const float* __restrict__ mb0, const float* __restrict__ mb1,
    const float* __restrict__ gb0, const float* __restrict__ gw1,
    const float* __restrict__ gb1, float* __restrict__ ws)
{
    __shared__ __align__(16) unsigned short xsl[64 * 136];
    __shared__ __align__(16) unsigned short hhl[64 * 136];
    __shared__ float msgl[64 * 68];
    __shared__ float ghl[64 * 68];
    __shared__ float gatel[64];
    __shared__ int   slotl[64];

    const int tid  = threadIdx.x;
    const int tok0 = blockIdx.x * 64;
    const int b    = tok0 >> 12;      // / L

    if (tid < 64) slotl[tid] = ((const int*)(ws + OFF_SLOT))[tok0 + tid];

    {
        int t = tid >> 2, q = tid & 3;
        unsigned short tmp[32];
        if (q < 2) {
            const float* Xp = X + (size_t)(tok0 + t) * D + q * 32;
            #pragma unroll
            for (int u = 0; u < 8; ++u) {
                float4 v = *(const float4*)(Xp + u * 4);
                tmp[u*4+0] = f2bf(v.x); tmp[u*4+1] = f2bf(v.y);
                tmp[u*4+2] = f2bf(v.z); tmp[u*4+3] = f2bf(v.w);
            }
        } else {
            const float* Sp = ws + OFF_SSUM + b * D + (q - 2) * 32;
            #pragma unroll
            for (int u = 0; u < 32; ++u) tmp[u] = f2bf(Sp[u]);
        }
        #pragma unroll
        for (int s = 0; s < 4; ++s)
            *(short8*)&xsl[t * 136 + (q * 4 + s) * 8] = *(const short8*)&tmp[s * 8];
    }
    __syncthreads();

    const int w  = tid >> 6;
    const int l  = tid & 63;
    const int lr = l & 15;
    const int lk = l >> 4;
    const unsigned short* wsu = (const unsigned short*)ws;

    // ---- GEMM1: H = gelu(XS @ mw0^T + mb0) ----
    {
        f32x4 acc[2][4];
        #pragma unroll
        for (int a_ = 0; a_ < 2; ++a_)
            #pragma unroll
            for (int b_ = 0; b_ < 4; ++b_) acc[a_][b_] = (f32x4){0.f, 0.f, 0.f, 0.f};

        for (int ks = 0; ks < 4; ++ks) {
            short8 a[4];
            #pragma unroll
            for (int tt = 0; tt < 4; ++tt)
                a[tt] = *(const short8*)&xsl[(tt * 16 + lr) * 136 + (ks * 4 + lk) * 8];
            #pragma unroll
            for (int jt2 = 0; jt2 < 2; ++jt2) {
                int jt = w * 2 + jt2;
                short8 bb = *(const short8*)&wsu[OFF_MW0B * 2 + ((jt * 4 + ks) * 64 + l) * 8];
                #pragma unroll
                for (int tt = 0; tt < 4; ++tt)
                    acc[jt2][tt] = __builtin_amdgcn_mfma_f32_16x16x32_bf16(a[tt], bb, acc[jt2][tt], 0, 0, 0);
            }
        }
        #pragma unroll
        for (int jt2 = 0; jt2 < 2; ++jt2) {
            int j = w * 32 + jt2 * 16 + lr;
            float bias = mb0[j];
            #pragma unroll
            for (int tt = 0; tt < 4; ++tt) {
                #pragma unroll
                for (int r = 0; r < 4; ++r) {
                    int t = tt * 16 + lk * 4 + r;
                    hhl[t * 136 + j] = f2bf(gelu_exact(acc[jt2][tt][r] + bias));
                }
            }
        }
    }
    __syncthreads();

    // ---- GEMM2: waves 0,1: msg ; waves 2,3: gate hidden ----
    {
        f32x4 acc[2][4];
        #pragma unroll
        for (int a_ = 0; a_ < 2; ++a_)
            #pragma unroll
            for (int b_ = 0; b_ < 4; ++b_) acc[a_][b_] = (f32x4){0.f, 0.f, 0.f, 0.f};

        const unsigned short* srcA = (w < 2) ? hhl : xsl;
        const int wb   = (w < 2) ? w : (w - 2);
        const int boff = (w < 2) ? OFF_MW1B * 2 : OFF_GW0B * 2;

        for (int ks = 0; ks < 4; ++ks) {
            short8 a[4];
            #pragma unroll
            for (int tt = 0; tt < 4; ++tt)
                a[tt] = *(const short8*)&srcA[(tt * 16 + lr) * 136 + (ks * 4 + lk) * 8];
            #pragma unroll
            for (int jt2 = 0; jt2 < 2; ++jt2) {
                int jt = wb * 2 + jt2;
                short8 bb = *(const short8*)&wsu[boff + ((jt * 4 + ks) * 64 + l) * 8];
                #pragma unroll
                for (int tt = 0; tt < 4; ++tt)
                    acc[jt2][tt] = __builtin_amdgcn_mfma_f32_16x16x32_bf16(a[tt], bb, acc[jt2][tt], 0, 0, 0);
            }
        }
        if (w < 2) {
            #pragma unroll
            for (int jt2 = 0; jt2 < 2; ++jt2) {
                int j = w * 32 + jt2 * 16 + lr;
                float bias = mb1[j];
                #pragma unroll
                for (int tt = 0; tt < 4; ++tt)
                    #pragma unroll
                    for (int r = 0; r < 4; ++r) {
                        int t = tt * 16 + lk * 4 + r;
                        msgl[t * 68 + j] = acc[jt2][tt][r] + bias;
                    }
            }
        } else {
            #pragma unroll
            for (int jt2 = 0; jt2 < 2; ++jt2) {
                int j = wb * 32 + jt2 * 16 + lr;
                float bias = gb0[j];
                #pragma unroll
                for (int tt = 0; tt < 4; ++tt)
                    #pragma unroll
                    for (int r = 0; r < 4; ++r) {
                        int t = tt * 16 + lk * 4 + r;
                        ghl[t * 68 + j] = gelu_exact(acc[jt2][tt][r] + bias);
                    }
            }
        }
    }
    __syncthreads();

    if (tid < 64) {
        float acc = gb1[0];
        for (int jj = 0; jj < D; ++jj) acc += ghl[tid * 68 + jj] * gw1[jj];
        gatel[tid] = 1.0f / (1.0f + expf(-acc));
    }
    __syncthreads();

    float* inc = ws + OFF_INC;
    #pragma unroll
    for (int i = tid; i < 64 * D; i += 256) {
        int t = i >> 6, d = i & 63;
        atomicAdd(&inc[((size_t)(b * NSLOT + slotl[t])) * D + d], msgl[t * 68 + d] * gatel[t]);
    }
}

// ---------------- update kernel: bf16 MFMA slot MLP + residual + layernorm ----------------
__global__ __launch_bounds__(256) void update_kernel(
    const float* __restrict__ S,
    const float* __restrict__ ub0, const float* __restrict__ ub1,
    const float* __restrict__ ln_w, const float* __restrict__ ln_b,
    const float* __restrict__ ws, float* __restrict__ out)
{
    __shared__ __align__(16) unsigned short rowl[32 * 136];
    __shared__ __align__(16) unsigned short uul[32 * 136];
    __shared__ float s32[32][69];
    __shared__ float dl[32][69];
    __shared__ float mu_s[32], rs_s[32];

    const int r0  = blockIdx.x * 32;   // flat over B*N
    const int tid = threadIdx.x;

    for (int idx = tid; idx < 32 * D; idx += 256) {
        int t = idx >> 6, d = idx & 63;
        size_t g = (size_t)(r0 + t) * D + d;
        float sv = S[g], iv = ws[OFF_INC + g];
        s32[t][d] = sv;
        rowl[t * 136 + d]     = f2bf(sv);
        rowl[t * 136 + D + d] = f2bf(iv);
    }
    __syncthreads();

    const int w  = tid >> 6;
    const int l  = tid & 63;
    const int lr = l & 15;
    const int lk = l >> 4;
    const unsigned short* wsu = (const unsigned short*)ws;

    // ---- U1: u = gelu(upd_in @ uw0^T + ub0), wave w -> col-tiles {2w, 2w+1} ----
    {
        f32x4 acc[2][2];
        #pragma unroll
        for (int c2 = 0; c2 < 2; ++c2) { acc[c2][0] = (f32x4){0.f,0.f,0.f,0.f}; acc[c2][1] = (f32x4){0.f,0.f,0.f,0.f}; }
        for (int ks = 0; ks < 4; ++ks) {
            short8 a[2];
            #pragma unroll
            for (int tt = 0; tt < 2; ++tt)
                a[tt] = *(const short8*)&rowl[(tt * 16 + lr) * 136 + (ks * 4 + lk) * 8];
            #pragma unroll
            for (int c2 = 0; c2 < 2; ++c2) {
                int jt = w * 2 + c2;
                short8 bb = *(const short8*)&wsu[OFF_UW0B * 2 + ((jt * 4 + ks) * 64 + l) * 8];
                #pragma unroll
                for (int tt = 0; tt < 2; ++tt)
                    acc[c2][tt] = __builtin_amdgcn_mfma_f32_16x16x32_bf16(a[tt], bb, acc[c2][tt], 0, 0, 0);
            }
        }
        #pragma unroll
        for (int c2 = 0; c2 < 2; ++c2) {
            int j = (w * 2 + c2) * 16 + lr;
            float bias = ub0[j];
            #pragma unroll
            for (int tt = 0; tt < 2; ++tt)
                #pragma unroll
                for (int r = 0; r < 4; ++r) {
                    int t = tt * 16 + lk * 4 + r;
                    uul[t * 136 + j] = f2bf(gelu_exact(acc[c2][tt][r] + bias));
                }
        }
    }
    __syncthreads();

    // ---- U2: delta = u @ uw1^T + ub1, wave w -> col-tile w ----
    {
        f32x4 acc[2];
        acc[0] = (f32x4){0.f,0.f,0.f,0.f}; acc[1] = (f32x4){0.f,0.f,0.f,0.f};
        for (int ks = 0; ks < 4; ++ks) {
            short8 a[2];
            #pragma unroll
            for (int tt = 0; tt < 2; ++tt)
                a[tt] = *(const short8*)&uul[(tt * 16 + lr) * 136 + (ks * 4 + lk) * 8];
            short8 bb = *(const short8*)&wsu[OFF_UW1B * 2 + ((w * 4 + ks) * 64 + l) * 8];
            #pragma unroll
            for (int tt = 0; tt < 2; ++tt)
                acc[tt] = __builtin_amdgcn_mfma_f32_16x16x32_bf16(a[tt], bb, acc[tt], 0, 0, 0);
        }
        int j = w * 16 + lr;
        float bias = ub1[j];
        #pragma unroll
        for (int tt = 0; tt < 2; ++tt)
            #pragma unroll
            for (int r = 0; r < 4; ++r) {
                int t = tt * 16 + lk * 4 + r;
                dl[t][j] = acc[tt][r] + bias;
            }
    }
    __syncthreads();

    if (tid < 32) {
        int t = tid;
        float m = 0.f;
        for (int d = 0; d < D; ++d) m += s32[t][d] + dl[t][d];
        m *= (1.0f / D);
        float v = 0.f;
        for (int d = 0; d < D; ++d) { float dd = s32[t][d] + dl[t][d] - m; v += dd * dd; }
        v *= (1.0f / D);
        mu_s[t] = m;
        rs_s[t] = rsqrtf(v + EPS);
    }
    __syncthreads();

    for (int idx = tid; idx < 32 * D; idx += 256) {
        int t = idx >> 6, d = idx & 63;
        out[(size_t)(r0 + t) * D + d] =
            (s32[t][d] + dl[t][d] - mu_s[t]) * rs_s[t] * ln_w[d] + ln_b[d];
    }
}

extern "C" void kernel_launch(void* const* d_in, const int* in_sizes, int n_in,
                              void* d_out, int out_size, void* d_ws, size_t ws_size,
                              hipStream_t stream)
{
    const float* X    = (const float*)d_in[0];
    const float* S    = (const float*)d_in[1];
    const float* Wg   = (const float*)d_in[2];
    const float* Ws   = (const float*)d_in[3];
    const float* mw0  = (const float*)d_in[4];
    const float* mb0  = (const float*)d_in[5];
    const float* mw1  = (const float*)d_in[6];
    const float* mb1  = (const float*)d_in[7];
    const float* gw0  = (const float*)d_in[8];
    const float* gb0  = (const float*)d_in[9];
    const float* gw1  = (const float*)d_in[10];
    const float* gb1  = (const float*)d_in[11];
    const float* uw0  = (const float*)d_in[12];
    const float* ub0  = (const float*)d_in[13];
    const float* uw1  = (const float*)d_in[14];
    const float* ub1  = (const float*)d_in[15];
    const float* ln_w = (const float*)d_in[16];
    const float* ln_b = (const float*)d_in[17];

    float* ws  = (float*)d_ws;
    float* out = (float*)d_out;

    hipMemsetAsync(ws + OFF_INC, 0, (size_t)B * NSLOT * D * sizeof(float), stream);

    prep_kernel<<<312, 256, 0, stream>>>(S, Wg, Ws, mw0, mw1, gw0, uw0, uw1, ws);
    routing_kernel<<<(B * L) / 64, 256, 0, stream>>>(X, ws);
    msg_kernel<<<(B * L) / 64, 256, 0, stream>>>(X, mb0, mb1, gb0, gw1, gb1, ws);
    update_kernel<<<(B * NSLOT) / 32, 256, 0, stream>>>(S, ub0, ub1, ln_w, ln_b, ws, out);
}